// Round 4
// baseline (295.069 us; speedup 1.0000x reference)
//
#include <hip/hip_runtime.h>
#include <hip/hip_bf16.h>

#define BIGF 99999999.0f
#define NPP 4096
#define BB 4
#define NQ 4
#define CAP 256

// ---------- helpers ----------

__device__ __forceinline__ float rl(float v, int l) {
    return __int_as_float(__builtin_amdgcn_readlane(__float_as_int(v), l));
}

template <typename T>
__device__ __forceinline__ T bitonic_sort64(T v, int lane) {
    #pragma unroll
    for (int k = 2; k <= 64; k <<= 1) {
        #pragma unroll
        for (int j = k >> 1; j > 0; j >>= 1) {
            T p = __shfl_xor(v, j);
            bool up  = ((lane & k) == 0);
            bool low = ((lane & j) == 0);
            T mn = (v < p) ? v : p;
            T mx = (v < p) ? p : v;
            v = (up == low) ? mn : mx;
        }
    }
    return v;
}

// ---------- kernel 0: per-point squared norms (+ zero zout) ----------

__global__ __launch_bounds__(256) void n2_kernel(const float* __restrict__ x,
                                                 float* __restrict__ n2tab,
                                                 float* __restrict__ zout) {
    int i = blockIdx.x * 256 + threadIdx.x;       // 0..16383
    if (blockIdx.x == 0) zout[threadIdx.x] = 0.f; // 256 floats
    const float4* p = (const float4*)(x + (long)i * 8);
    float4 a = p[0], c = p[1];
    float s = 0.f;
    s = fmaf(a.x, a.x, s); s = fmaf(a.y, a.y, s);
    s = fmaf(a.z, a.z, s); s = fmaf(a.w, a.w, s);
    s = fmaf(c.x, c.x, s); s = fmaf(c.y, c.y, s);
    s = fmaf(c.z, c.z, s); s = fmaf(c.w, c.w, s);
    n2tab[i] = s;
}

// ---------- kernel 1: z projections ----------

__global__ void zz_kernel(const float* __restrict__ z,
                          const float* __restrict__ Wmz, const float* __restrict__ bmz,
                          const float* __restrict__ Wvz, const float* __restrict__ bvz,
                          float* __restrict__ zzm, float* __restrict__ zzv) {
    int b = blockIdx.x, l = threadIdx.x;
    float sv = 0.f;
    for (int p = 0; p < 64; ++p) sv = fmaf(z[b * 64 + p], Wvz[p * 64 + l], sv);
    zzv[b * 64 + l] = sv + bvz[l];
    if (l < 8) {
        float sm = 0.f;
        for (int p = 0; p < 64; ++p) sm = fmaf(z[b * 64 + p], Wmz[p * 8 + l], sm);
        zzm[b * 8 + l] = sm + bmz[l];
    }
}

// ---------- kernel 2a: per-query threshold (lane = query) ----------
// Block: 512 threads = 8 waves, all serving the same 64 queries (one per lane).
// Wave w scans candidates [w*512, w*512+512), keeping 2 substream minima
// (i&1) of the patched d2-key -> 16 disjoint substreams of 256 candidates.
// T~(q) = max of the 16 substream minima: >=16 distinct non-self candidates
// have key <= T~, so {key <= T~} provably contains the exact top-16.

__global__ __launch_bounds__(512) void thr_kernel(const float* __restrict__ x,
                                                  const float* __restrict__ n2tab,
                                                  unsigned* __restrict__ Ttab) {
    __shared__ unsigned mins_s[16][64];

    int lane = threadIdx.x & 63;
    int wid  = threadIdx.x >> 6;              // 0..7
    int qg   = blockIdx.x * 64 + lane;        // this lane's query
    int b    = qg >> 12;
    int qloc = qg & 4095;
    const float* xb = x + (long)b * NPP * 8;
    const float* nb = n2tab + b * NPP;

    float qf[8];
    #pragma unroll
    for (int f = 0; f < 8; ++f) qf[f] = xb[(long)qloc * 8 + f];
    float n2i = nb[qloc];
    const unsigned BIGB = __float_as_uint(BIGF);

    unsigned m0 = 0xFFFFFFFFu, m1 = 0xFFFFFFFFu;
    int j0 = wid * 512;
    #pragma unroll 4
    for (int i = 0; i < 512; ++i) {
        int j = j0 + i;                        // wave-uniform -> broadcast loads
        const float4* pj = (const float4*)(xb + (long)j * 8);
        float4 a = pj[0], c = pj[1];
        float n2j = nb[j];
        float dot = 0.f;
        dot = fmaf(qf[0], a.x, dot); dot = fmaf(qf[1], a.y, dot);
        dot = fmaf(qf[2], a.z, dot); dot = fmaf(qf[3], a.w, dot);
        dot = fmaf(qf[4], c.x, dot); dot = fmaf(qf[5], c.y, dot);
        dot = fmaf(qf[6], c.z, dot); dot = fmaf(qf[7], c.w, dot);
        float d2 = fmaf(-2.0f, dot, n2i + n2j);
        unsigned kb = __float_as_uint(d2);
        kb = (j == qloc) ? BIGB : kb;          // self -> BIG (matches gather)
        if (i & 1) { m1 = (kb < m1) ? kb : m1; }
        else       { m0 = (kb < m0) ? kb : m0; }
    }
    mins_s[wid * 2 + 0][lane] = m0;
    mins_s[wid * 2 + 1][lane] = m1;
    __syncthreads();

    if (wid == 0) {
        unsigned T = 0;
        #pragma unroll
        for (int i = 0; i < 16; ++i) {
            unsigned v = mins_s[i][lane];
            T = (v > T) ? v : T;
        }
        Ttab[blockIdx.x * 64 + lane] = T;
    }
}

// ---------- kernel 2b: single-pass gather + sort (lane = candidate) ----------
// NQ=4 queries per wave. Append (key<<32)|j to a per-query LDS buffer iff
// key <= T~(q) (mbcnt compaction). One u64 bitonic sort yields the exact
// top-16 ascending with the reference's lower-index tie rule.

__global__ __launch_bounds__(256) void knn_kernel(const float* __restrict__ x,
                                                  const float* __restrict__ n2tab,
                                                  const unsigned* __restrict__ Ttab,
                                                  int* __restrict__ idx_out) {
    __shared__ unsigned long long cand[4][NQ][CAP];   // 32 KB

    int lane = threadIdx.x & 63;
    int wid  = threadIdx.x >> 6;
    int gw   = blockIdx.x * 4 + wid;      // 0..4095
    int q0   = gw * NQ;
    int b    = q0 >> 12;
    int qloc = q0 & 4095;
    const float* xb = x + (long)b * NPP * 8;
    const float* nb = n2tab + b * NPP;

    float qf[NQ][8];
    float n2i[NQ];
    unsigned Tq[NQ];
    int cnt[NQ], selfT[NQ], selfL[NQ];
    #pragma unroll
    for (int q = 0; q < NQ; ++q) {
        #pragma unroll
        for (int f = 0; f < 8; ++f) qf[q][f] = xb[(qloc + q) * 8 + f];
        n2i[q]   = nb[qloc + q];
        Tq[q]    = Ttab[q0 + q];
        cnt[q]   = 0;
        selfT[q] = (qloc + q) >> 6;
        selfL[q] = (qloc + q) & 63;
    }
    const unsigned BIGB = __float_as_uint(BIGF);

    for (int t = 0; t < 64; ++t) {
        int j = t * 64 + lane;
        const float4* pj = (const float4*)(xb + (long)j * 8);
        float4 a = pj[0], c = pj[1];
        float n2j = nb[j];
        #pragma unroll
        for (int q = 0; q < NQ; ++q) {
            float dot = 0.f;
            dot = fmaf(qf[q][0], a.x, dot); dot = fmaf(qf[q][1], a.y, dot);
            dot = fmaf(qf[q][2], a.z, dot); dot = fmaf(qf[q][3], a.w, dot);
            dot = fmaf(qf[q][4], c.x, dot); dot = fmaf(qf[q][5], c.y, dot);
            dot = fmaf(qf[q][6], c.z, dot); dot = fmaf(qf[q][7], c.w, dot);
            float d2 = fmaf(-2.0f, dot, n2i[q] + n2j);
            unsigned kb = __float_as_uint(d2);
            if (t == selfT[q]) {                       // uniform branch, rare
                kb = (lane == selfL[q]) ? BIGB : kb;
            }
            bool pred = (kb <= Tq[q]);
            unsigned long long m = __ballot(pred);
            if (m) {
                unsigned mlo = (unsigned)m, mhi = (unsigned)(m >> 32);
                int below = __builtin_amdgcn_mbcnt_hi(mhi,
                             __builtin_amdgcn_mbcnt_lo(mlo, 0));
                int ofs = cnt[q] + below;
                if (pred && ofs < CAP) {
                    cand[wid][q][ofs] = ((unsigned long long)kb << 32) | (unsigned)j;
                }
                cnt[q] += __popcll(m);
            }
        }
    }

    // extract exact top-16 per query (same-wave LDS RAW: lgkmcnt handled)
    #pragma unroll 1
    for (int q = 0; q < NQ; ++q) {
        int n = cnt[q] > CAP ? CAP : cnt[q];
        unsigned long long v = (lane < n) ? cand[wid][q][lane] : ~0ull;
        unsigned long long R = bitonic_sort64(v, lane);
        int nch = (n + 63) >> 6;
        #pragma unroll 1
        for (int cc = 1; cc < nch; ++cc) {            // ~never taken (n<=64 typ.)
            int base = cc << 6;
            unsigned long long w2 = (base + lane < n) ? cand[wid][q][base + lane] : ~0ull;
            w2 = bitonic_sort64(w2, lane);
            unsigned long long vt = __shfl(w2, lane - 16);
            unsigned long long comb = (lane < 16) ? R : ((lane < 32) ? vt : ~0ull);
            R = bitonic_sort64(comb, lane);
        }
        if (lane < 16) {
            idx_out[(long)(q0 + q) * 16 + lane] = (int)(R & 0xFFFFFFFFull);
        }
    }
}

// ---------- kernel 3: features + output heads ----------

__global__ __launch_bounds__(256) void feat_kernel(
    const float* __restrict__ x, const int* __restrict__ idxw,
    const float* __restrict__ Wm2, const float* __restrict__ bm2,
    const float* __restrict__ Wm3, const float* __restrict__ bm3,
    const float* __restrict__ Wv2, const float* __restrict__ bv2,
    const float* __restrict__ Wv3, const float* __restrict__ bv3,
    const float* __restrict__ Wmx, const float* __restrict__ bmx,
    const float* __restrict__ Wvx, const float* __restrict__ bvx,
    const float* __restrict__ zzm, const float* __restrict__ zzv,
    float* __restrict__ xout, float* __restrict__ zout)
{
    int lane = threadIdx.x & 63;
    int wid  = threadIdx.x >> 6;
    int pn   = blockIdx.x * 4 + wid;          // global point id
    int b    = pn >> 12;
    const float* xb = x + b * NPP * 8;

    __shared__ float xg_s[4][16][8];
    __shared__ float mm_s[4][15][36];         // stride 36: conflict-free
    __shared__ float wmx_s[32][8];
    __shared__ float bzm_s[8];
    __shared__ float zpart[4][64];

    if (threadIdx.x < 256) {
        wmx_s[threadIdx.x >> 3][threadIdx.x & 7] = Wmx[threadIdx.x];
    }
    if (threadIdx.x < 8) bzm_s[threadIdx.x] = bmx[threadIdx.x] + zzm[b * 8 + threadIdx.x];

    int k = lane & 15;
    float w20 = Wm2[k], w21 = Wm2[16 + k], bb2 = bm2[k];
    float w30 = Wm3[k], w31 = Wm3[16 + k], w32 = Wm3[32 + k], bb3 = bm3[k];
    float u20 = Wv2[k], u21 = Wv2[16 + k], cc2 = bv2[k];
    float u30 = Wv3[k], u31 = Wv3[16 + k], u32 = Wv3[32 + k], cc3 = bv3[k];
    float wvx[32];
    #pragma unroll
    for (int c = 0; c < 32; ++c) wvx[c] = Wvx[c * 64 + lane];
    float bz3 = bvx[lane] + zzv[b * 64 + lane];

    if (lane < 16) {
        int myid = idxw[(long)pn * 16 + lane];
        const float4* ps = (const float4*)(xb + (long)myid * 8);
        float4 a = ps[0], c4 = ps[1];
        *((float4*)&xg_s[wid][lane][0]) = a;
        *((float4*)&xg_s[wid][lane][4]) = c4;
    }
    __syncthreads();

    float g0[8];
    #pragma unroll
    for (int f = 0; f < 8; ++f) g0[f] = xg_s[wid][0][f];

    float am2[4], am3[4], av2[4], av3[4];
    #pragma unroll
    for (int p = 0; p < 4; ++p) {
        int rg = lane >> 4;
        int r  = p * 4 + rg;
        int rc = (r < 14) ? r : 14;
        int i2  = rc + 1;
        int i3a = (rc < 14) ? 1 : 2;
        int i3b = (rc < 14) ? rc + 2 : 3;
        const float* G1  = xg_s[wid][i2];
        const float* G3a = xg_s[wid][i3a];
        const float* G3b = xg_s[wid][i3b];
        float s2 = 0.f, s3 = 0.f, t2 = 0.f, t3 = 0.f;
        #pragma unroll
        for (int d = 0; d < 8; ++d) {
            float gz = g0[d], g1 = G1[d], ga = G3a[d], gb = G3b[d];
            float y2 = fmaf(gz, w20, fmaf(g1, w21, bb2));
            s2 += fmaxf(y2, 0.f);
            float y3 = fmaf(gz, w30, fmaf(ga, w31, fmaf(gb, w32, bb3)));
            s3 += fmaxf(y3, 0.f);
            float z2 = fmaf(gz, u20, fmaf(g1, u21, cc2));
            t2 += fmaxf(z2, 0.f);
            float z3 = fmaf(gz, u30, fmaf(ga, u31, fmaf(gb, u32, cc3)));
            t3 += fmaxf(z3, 0.f);
        }
        am2[p] = s2 * 0.125f; am3[p] = s3 * 0.125f;
        av2[p] = t2 * 0.125f; av3[p] = t3 * 0.125f;
        if (r < 15) {
            mm_s[wid][r][k]      = am2[p];
            mm_s[wid][r][16 + k] = am3[p];
        }
    }
    __syncthreads();

    float xa = 0.f;
    #pragma unroll
    for (int half = 0; half < 2; ++half) {
        int r   = (lane >> 3) + half * 8;
        int doo = lane & 7;
        float s = 0.f;
        if (r < 15) {
            s = bzm_s[doo];
            #pragma unroll
            for (int c = 0; c < 32; ++c)
                s = fmaf(mm_s[wid][r][c], wmx_s[c][doo], s);
            s = fmaxf(s, 0.f);
        }
        xa += s;
    }
    xa += __shfl_xor(xa, 8);
    xa += __shfl_xor(xa, 16);
    xa += __shfl_xor(xa, 32);
    float xv = xa * (1.0f / 15.0f);
    if (lane < 8) xout[(long)pn * 8 + lane] = xv;

    float za = 0.f;
    #pragma unroll
    for (int r = 0; r < 15; ++r) {
        float s = bz3;
        const int p  = r >> 2;
        const int sb = (r & 3) * 16;
        #pragma unroll
        for (int c = 0; c < 16; ++c)
            s = fmaf(rl(av2[p], sb + c), wvx[c], s);
        #pragma unroll
        for (int c = 0; c < 16; ++c)
            s = fmaf(rl(av3[p], sb + c), wvx[16 + c], s);
        za += fmaxf(s, 0.f);
    }
    za *= (1.0f / 61440.0f);

    zpart[wid][lane] = za;
    __syncthreads();
    if (wid == 0) {
        float ssum = zpart[0][lane] + zpart[1][lane] + zpart[2][lane] + zpart[3][lane];
        atomicAdd(&zout[b * 64 + lane], ssum);
    }
}

// ---------- launcher ----------

extern "C" void kernel_launch(void* const* d_in, const int* in_sizes, int n_in,
                              void* d_out, int out_size, void* d_ws, size_t ws_size,
                              hipStream_t stream) {
    const float* x   = (const float*)d_in[0];
    const float* z   = (const float*)d_in[1];
    const float* Wm2 = (const float*)d_in[2];
    const float* bm2 = (const float*)d_in[3];
    const float* Wm3 = (const float*)d_in[4];
    const float* bm3 = (const float*)d_in[5];
    const float* Wv2 = (const float*)d_in[6];
    const float* bv2 = (const float*)d_in[7];
    const float* Wv3 = (const float*)d_in[8];
    const float* bv3 = (const float*)d_in[9];
    const float* Wmx = (const float*)d_in[10];
    const float* bmx = (const float*)d_in[11];
    const float* Wvx = (const float*)d_in[12];
    const float* bvx = (const float*)d_in[13];
    const float* Wmz = (const float*)d_in[14];
    const float* bmz = (const float*)d_in[15];
    const float* Wvz = (const float*)d_in[16];
    const float* bvz = (const float*)d_in[17];

    float* out  = (float*)d_out;
    int*   idxw = (int*)d_ws;                                   // 1 MB
    float* zzm  = (float*)((char*)d_ws + (size_t)BB * NPP * 16 * 4);
    float* zzv  = zzm + BB * 8;
    float* n2t  = zzv + BB * 64;                                // 64 KB
    unsigned* Ttab = (unsigned*)(n2t + BB * NPP);               // 64 KB
    float* xout = out;                 // B*NP*8 = 131072 floats
    float* zout = out + BB * NPP * 8;  // B*64 = 256 floats

    n2_kernel<<<dim3(BB * NPP / 256), dim3(256), 0, stream>>>(x, n2t, zout);
    zz_kernel<<<dim3(BB), dim3(64), 0, stream>>>(z, Wmz, bmz, Wvz, bvz, zzm, zzv);
    thr_kernel<<<dim3(BB * NPP / 64), dim3(512), 0, stream>>>(x, n2t, Ttab);
    knn_kernel<<<dim3(BB * NPP / (4 * NQ)), dim3(256), 0, stream>>>(x, n2t, Ttab, idxw);
    feat_kernel<<<dim3(4096), dim3(256), 0, stream>>>(
        x, idxw, Wm2, bm2, Wm3, bm3, Wv2, bv2, Wv3, bv3,
        Wmx, bmx, Wvx, bvx, zzm, zzv, xout, zout);
}

// Round 5
// 243.418 us; speedup vs baseline: 1.2122x; 1.2122x over previous
//
#include <hip/hip_runtime.h>
#include <hip/hip_bf16.h>

#define BIGF 99999999.0f
#define NPP 4096
#define BB 4
#define NQ 4
#define CAP 128

// ---------- helpers ----------

template <typename T>
__device__ __forceinline__ T bitonic_sort64(T v, int lane) {
    #pragma unroll
    for (int k = 2; k <= 64; k <<= 1) {
        #pragma unroll
        for (int j = k >> 1; j > 0; j >>= 1) {
            T p = __shfl_xor(v, j);
            bool up  = ((lane & k) == 0);
            bool low = ((lane & j) == 0);
            T mn = (v < p) ? v : p;
            T mx = (v < p) ? p : v;
            v = (up == low) ? mn : mx;
        }
    }
    return v;
}

// ---------- kernel 0: per-point squared norms + z projections + zero zout ----------

__global__ __launch_bounds__(256) void n2_kernel(
    const float* __restrict__ x, const float* __restrict__ z,
    const float* __restrict__ Wmz, const float* __restrict__ bmz,
    const float* __restrict__ Wvz, const float* __restrict__ bvz,
    float* __restrict__ n2tab, float* __restrict__ zzm, float* __restrict__ zzv,
    float* __restrict__ zout)
{
    int i = blockIdx.x * 256 + threadIdx.x;       // 0..16383
    const float4* p = (const float4*)(x + (long)i * 8);
    float4 a = p[0], c = p[1];
    float s = 0.f;
    s = fmaf(a.x, a.x, s); s = fmaf(a.y, a.y, s);
    s = fmaf(a.z, a.z, s); s = fmaf(a.w, a.w, s);
    s = fmaf(c.x, c.x, s); s = fmaf(c.y, c.y, s);
    s = fmaf(c.z, c.z, s); s = fmaf(c.w, c.w, s);
    n2tab[i] = s;

    if (blockIdx.x == 0) {
        zout[threadIdx.x] = 0.f;                  // 256 floats
        int b = threadIdx.x >> 6, l = threadIdx.x & 63;
        float sv = 0.f;
        for (int q = 0; q < 64; ++q) sv = fmaf(z[b * 64 + q], Wvz[q * 64 + l], sv);
        zzv[b * 64 + l] = sv + bvz[l];
        if (threadIdx.x < 32) {
            int bm = threadIdx.x >> 3, lm = threadIdx.x & 7;
            float sm = 0.f;
            for (int q = 0; q < 64; ++q) sm = fmaf(z[bm * 64 + q], Wmz[q * 8 + lm], sm);
            zzm[bm * 8 + lm] = sm + bmz[lm];
        }
    }
}

// ---------- kernel 1: exact knn top-16, NQ=4 queries per wave ----------
// Pass A: per-lane u64 (key<<32|j) minimum over the lane's 64-candidate
// substream; u64 bitonic sort of the 64 lane-minima -> T = key of 16th
// smallest. Every true top-16 key <= T (16 distinct lane-min witnesses).
// Pass B: recompute keys (bit-identical fmaf chain), wave __any early-out,
// rare LDS atomic-append of (key,j); final u64 bitonic sort (2-chunk merge
// if count>64) -> exact top-16 ascending, reference tie order (lower index).

__global__ __launch_bounds__(256) void knn_kernel(const float* __restrict__ x,
                                                  const float* __restrict__ n2tab,
                                                  int* __restrict__ idx_out) {
    __shared__ unsigned long long cand[4][NQ][CAP];   // 16 KB
    __shared__ unsigned cnt_s[4][NQ];

    int lane = threadIdx.x & 63;
    int wid  = threadIdx.x >> 6;
    if (lane < NQ) cnt_s[wid][lane] = 0;              // per-wave buffer

    int gw   = blockIdx.x * 4 + wid;      // 0..4095
    int q0   = gw * NQ;
    int b    = q0 >> 12;
    int qloc = q0 & 4095;
    const float* xb = x + (long)b * NPP * 8;
    const float* nb = n2tab + b * NPP;

    float qf[NQ][8];
    float n2i[NQ];
    int selfT[NQ], selfL[NQ];
    #pragma unroll
    for (int q = 0; q < NQ; ++q) {
        #pragma unroll
        for (int f = 0; f < 8; ++f) qf[q][f] = xb[(qloc + q) * 8 + f];
        n2i[q]   = nb[qloc + q];
        selfT[q] = (qloc + q) >> 6;
        selfL[q] = (qloc + q) & 63;
    }
    const unsigned BIGB = __float_as_uint(BIGF);

    // ---- pass A: per-lane u64 min ----
    unsigned long long mn[NQ];
    #pragma unroll
    for (int q = 0; q < NQ; ++q) mn[q] = ~0ull;

    #pragma unroll 2
    for (int t = 0; t < 64; ++t) {
        int j = t * 64 + lane;
        const float4* pj = (const float4*)(xb + (long)j * 8);
        float4 a = pj[0], c = pj[1];
        float n2j = nb[j];
        #pragma unroll
        for (int q = 0; q < NQ; ++q) {
            float dot = 0.f;
            dot = fmaf(qf[q][0], a.x, dot); dot = fmaf(qf[q][1], a.y, dot);
            dot = fmaf(qf[q][2], a.z, dot); dot = fmaf(qf[q][3], a.w, dot);
            dot = fmaf(qf[q][4], c.x, dot); dot = fmaf(qf[q][5], c.y, dot);
            dot = fmaf(qf[q][6], c.z, dot); dot = fmaf(qf[q][7], c.w, dot);
            float d2 = fmaf(-2.0f, dot, n2i[q] + n2j);
            unsigned kb = (d2 <= 0.0f) ? BIGB : __float_as_uint(d2);
            if (t == selfT[q]) {                       // uniform, 1-in-64
                kb = (lane == selfL[q]) ? BIGB : kb;
            }
            unsigned long long key = ((unsigned long long)kb << 32) | (unsigned)j;
            mn[q] = (key < mn[q]) ? key : mn[q];
        }
    }

    // thresholds: key of the 16th smallest lane-minimum
    unsigned T[NQ];
    #pragma unroll
    for (int q = 0; q < NQ; ++q) {
        unsigned long long s = bitonic_sort64(mn[q], lane);
        T[q] = (unsigned)(__shfl(s, 15) >> 32);
    }

    // ---- pass B: recompute + rare atomic append ----
    #pragma unroll 2
    for (int t = 0; t < 64; ++t) {
        int j = t * 64 + lane;
        const float4* pj = (const float4*)(xb + (long)j * 8);
        float4 a = pj[0], c = pj[1];
        float n2j = nb[j];
        unsigned kb[NQ];
        bool hit = false;
        #pragma unroll
        for (int q = 0; q < NQ; ++q) {
            float dot = 0.f;
            dot = fmaf(qf[q][0], a.x, dot); dot = fmaf(qf[q][1], a.y, dot);
            dot = fmaf(qf[q][2], a.z, dot); dot = fmaf(qf[q][3], a.w, dot);
            dot = fmaf(qf[q][4], c.x, dot); dot = fmaf(qf[q][5], c.y, dot);
            dot = fmaf(qf[q][6], c.z, dot); dot = fmaf(qf[q][7], c.w, dot);
            float d2 = fmaf(-2.0f, dot, n2i[q] + n2j);
            unsigned k = (d2 <= 0.0f) ? BIGB : __float_as_uint(d2);
            if (t == selfT[q]) {
                k = (lane == selfL[q]) ? BIGB : k;
            }
            kb[q] = k;
            hit |= (k <= T[q]);
        }
        if (__any(hit)) {
            #pragma unroll
            for (int q = 0; q < NQ; ++q) {
                if (kb[q] <= T[q]) {
                    unsigned old = atomicAdd(&cnt_s[wid][q], 1u);
                    if (old < CAP) {
                        cand[wid][q][old] =
                            ((unsigned long long)kb[q] << 32) | (unsigned)j;
                    }
                }
            }
        }
    }

    // ---- final: sort candidates, emit top-16 (append order irrelevant) ----
    #pragma unroll 1
    for (int q = 0; q < NQ; ++q) {
        unsigned nc = cnt_s[wid][q];
        int n = nc > CAP ? CAP : (int)nc;
        unsigned long long v = (lane < n) ? cand[wid][q][lane] : ~0ull;
        unsigned long long R = bitonic_sort64(v, lane);
        if (n > 64) {                                   // rare 2nd chunk
            unsigned long long w2 = (64 + lane < n) ? cand[wid][q][64 + lane] : ~0ull;
            w2 = bitonic_sort64(w2, lane);
            unsigned long long vt = __shfl(w2, lane - 16);
            unsigned long long comb = (lane < 16) ? R : ((lane < 32) ? vt : ~0ull);
            R = bitonic_sort64(comb, lane);
        }
        if (lane < 16) {
            idx_out[(long)(q0 + q) * 16 + lane] = (int)(R & 0xFFFFFFFFull);
        }
    }
}

// ---------- kernel 2: features + output heads ----------
// One wave per point. Stage1 writes m-moments AND v-moments to LDS
// (stride-68 rows, 16B aligned). Stage2: x-head via float4 LDS reads.
// Stage3: z-head via broadcast ds_read_b128 (no readlane).

__global__ __launch_bounds__(256) void feat_kernel(
    const float* __restrict__ x, const int* __restrict__ idxw,
    const float* __restrict__ Wm2, const float* __restrict__ bm2,
    const float* __restrict__ Wm3, const float* __restrict__ bm3,
    const float* __restrict__ Wv2, const float* __restrict__ bv2,
    const float* __restrict__ Wv3, const float* __restrict__ bv3,
    const float* __restrict__ Wmx, const float* __restrict__ bmx,
    const float* __restrict__ Wvx, const float* __restrict__ bvx,
    const float* __restrict__ zzm, const float* __restrict__ zzv,
    float* __restrict__ xout, float* __restrict__ zout)
{
    int lane = threadIdx.x & 63;
    int wid  = threadIdx.x >> 6;
    int pn   = blockIdx.x * 4 + wid;          // global point id
    int b    = pn >> 12;
    const float* xb = x + b * NPP * 8;

    __shared__ float xg_s[4][16][8];
    __shared__ float mo_s[4][15][68];         // cols 0..31 m-moments, 32..63 v-moments
    __shared__ float wmx_s[32][8];
    __shared__ float bzm_s[8];
    __shared__ float zpart[4][64];

    if (threadIdx.x < 256) {
        wmx_s[threadIdx.x >> 3][threadIdx.x & 7] = Wmx[threadIdx.x];
    }
    if (threadIdx.x < 8) bzm_s[threadIdx.x] = bmx[threadIdx.x] + zzm[b * 8 + threadIdx.x];

    int k = lane & 15;
    float w20 = Wm2[k], w21 = Wm2[16 + k], bb2 = bm2[k];
    float w30 = Wm3[k], w31 = Wm3[16 + k], w32 = Wm3[32 + k], bb3 = bm3[k];
    float u20 = Wv2[k], u21 = Wv2[16 + k], cc2 = bv2[k];
    float u30 = Wv3[k], u31 = Wv3[16 + k], u32 = Wv3[32 + k], cc3 = bv3[k];
    float wvx[32];
    #pragma unroll
    for (int c = 0; c < 32; ++c) wvx[c] = Wvx[c * 64 + lane];
    float bz3 = bvx[lane] + zzv[b * 64 + lane];

    if (lane < 16) {
        int myid = idxw[(long)pn * 16 + lane];
        const float4* ps = (const float4*)(xb + (long)myid * 8);
        float4 a = ps[0], c4 = ps[1];
        *((float4*)&xg_s[wid][lane][0]) = a;
        *((float4*)&xg_s[wid][lane][4]) = c4;
    }
    __syncthreads();

    float g0[8];
    #pragma unroll
    for (int f = 0; f < 8; ++f) g0[f] = xg_s[wid][0][f];

    // stage 1: moments (mean over d folded as exact *0.125)
    #pragma unroll
    for (int p = 0; p < 4; ++p) {
        int rg = lane >> 4;
        int r  = p * 4 + rg;
        int rc = (r < 14) ? r : 14;
        int i2  = rc + 1;
        int i3a = (rc < 14) ? 1 : 2;
        int i3b = (rc < 14) ? rc + 2 : 3;
        const float* G1  = xg_s[wid][i2];
        const float* G3a = xg_s[wid][i3a];
        const float* G3b = xg_s[wid][i3b];
        float s2 = 0.f, s3 = 0.f, t2 = 0.f, t3 = 0.f;
        #pragma unroll
        for (int d = 0; d < 8; ++d) {
            float gz = g0[d], g1 = G1[d], ga = G3a[d], gb = G3b[d];
            float y2 = fmaf(gz, w20, fmaf(g1, w21, bb2));
            s2 += fmaxf(y2, 0.f);
            float y3 = fmaf(gz, w30, fmaf(ga, w31, fmaf(gb, w32, bb3)));
            s3 += fmaxf(y3, 0.f);
            float z2 = fmaf(gz, u20, fmaf(g1, u21, cc2));
            t2 += fmaxf(z2, 0.f);
            float z3 = fmaf(gz, u30, fmaf(ga, u31, fmaf(gb, u32, cc3)));
            t3 += fmaxf(z3, 0.f);
        }
        if (r < 15) {
            mo_s[wid][r][k]      = s2 * 0.125f;
            mo_s[wid][r][16 + k] = s3 * 0.125f;
            mo_s[wid][r][32 + k] = t2 * 0.125f;
            mo_s[wid][r][48 + k] = t3 * 0.125f;
        }
    }
    __syncthreads();

    // stage 2: x head. lane=(r-group, do); two halves cover r=0..15 (15 masked).
    float xa = 0.f;
    #pragma unroll
    for (int half = 0; half < 2; ++half) {
        int r   = (lane >> 3) + half * 8;
        int doo = lane & 7;
        float s = 0.f;
        if (r < 15) {
            s = bzm_s[doo];
            #pragma unroll
            for (int cc = 0; cc < 8; ++cc) {
                float4 v = *(const float4*)&mo_s[wid][r][cc * 4];
                s = fmaf(v.x, wmx_s[cc * 4 + 0][doo], s);
                s = fmaf(v.y, wmx_s[cc * 4 + 1][doo], s);
                s = fmaf(v.z, wmx_s[cc * 4 + 2][doo], s);
                s = fmaf(v.w, wmx_s[cc * 4 + 3][doo], s);
            }
            s = fmaxf(s, 0.f);
        }
        xa += s;
    }
    xa += __shfl_xor(xa, 8);
    xa += __shfl_xor(xa, 16);
    xa += __shfl_xor(xa, 32);
    float xv = xa * (1.0f / 15.0f);
    if (lane < 8) xout[(long)pn * 8 + lane] = xv;

    // stage 3: z head. lane = nm; broadcast float4 reads of v-moments.
    float za = 0.f;
    #pragma unroll 1
    for (int r = 0; r < 15; ++r) {
        const float* row = &mo_s[wid][r][32];
        float s = bz3;
        #pragma unroll
        for (int cc = 0; cc < 8; ++cc) {
            float4 v = *(const float4*)(row + cc * 4);
            s = fmaf(v.x, wvx[cc * 4 + 0], s);
            s = fmaf(v.y, wvx[cc * 4 + 1], s);
            s = fmaf(v.z, wvx[cc * 4 + 2], s);
            s = fmaf(v.w, wvx[cc * 4 + 3], s);
        }
        za += fmaxf(s, 0.f);
    }
    za *= (1.0f / 61440.0f);

    zpart[wid][lane] = za;
    __syncthreads();
    if (wid == 0) {
        float ssum = zpart[0][lane] + zpart[1][lane] + zpart[2][lane] + zpart[3][lane];
        atomicAdd(&zout[b * 64 + lane], ssum);
    }
}

// ---------- launcher ----------

extern "C" void kernel_launch(void* const* d_in, const int* in_sizes, int n_in,
                              void* d_out, int out_size, void* d_ws, size_t ws_size,
                              hipStream_t stream) {
    const float* x   = (const float*)d_in[0];
    const float* z   = (const float*)d_in[1];
    const float* Wm2 = (const float*)d_in[2];
    const float* bm2 = (const float*)d_in[3];
    const float* Wm3 = (const float*)d_in[4];
    const float* bm3 = (const float*)d_in[5];
    const float* Wv2 = (const float*)d_in[6];
    const float* bv2 = (const float*)d_in[7];
    const float* Wv3 = (const float*)d_in[8];
    const float* bv3 = (const float*)d_in[9];
    const float* Wmx = (const float*)d_in[10];
    const float* bmx = (const float*)d_in[11];
    const float* Wvx = (const float*)d_in[12];
    const float* bvx = (const float*)d_in[13];
    const float* Wmz = (const float*)d_in[14];
    const float* bmz = (const float*)d_in[15];
    const float* Wvz = (const float*)d_in[16];
    const float* bvz = (const float*)d_in[17];

    float* out  = (float*)d_out;
    int*   idxw = (int*)d_ws;                                   // 1 MB
    float* zzm  = (float*)((char*)d_ws + (size_t)BB * NPP * 16 * 4);
    float* zzv  = zzm + BB * 8;
    float* n2t  = zzv + BB * 64;                                // 64 KB
    float* xout = out;                 // B*NP*8 = 131072 floats
    float* zout = out + BB * NPP * 8;  // B*64 = 256 floats

    n2_kernel<<<dim3(BB * NPP / 256), dim3(256), 0, stream>>>(
        x, z, Wmz, bmz, Wvz, bvz, n2t, zzm, zzv, zout);
    knn_kernel<<<dim3(BB * NPP / (4 * NQ)), dim3(256), 0, stream>>>(x, n2t, idxw);
    feat_kernel<<<dim3(4096), dim3(256), 0, stream>>>(
        x, idxw, Wm2, bm2, Wm3, bm3, Wv2, bv2, Wv3, bv3,
        Wmx, bmx, Wvx, bvx, zzm, zzv, xout, zout);
}